// Round 1
// baseline (9698.621 us; speedup 1.0000x reference)
//
#include <hip/hip_runtime.h>
#include <hip/hip_bf16.h>

// GraphSAGE 3-layer, N=50000 nodes, E=400000 edges, dims 512->512->512->128.
// Baseline: fp32 everywhere.
//  - deg/inv_deg computed once (graph identical across layers)
//  - edge-parallel scatter-add with f32 atomics (device scope, XCD-safe)
//  - fused GEMM: C = (agg*inv_deg)@W_l + X@W_r + b, optional relu
//  - in-place log_softmax on d_out

#define N_NODES 50000
#define N_EDGES 400000

__global__ __launch_bounds__(256) void zero4_kernel(float4* __restrict__ p, int n4) {
    int i = blockIdx.x * 256 + threadIdx.x;
    if (i < n4) p[i] = make_float4(0.f, 0.f, 0.f, 0.f);
}

__global__ __launch_bounds__(256) void deg_kernel(const int* __restrict__ dst,
                                                  float* __restrict__ deg, int E) {
    int e = blockIdx.x * 256 + threadIdx.x;
    if (e < E) atomicAdd(&deg[dst[e]], 1.0f);
}

__global__ __launch_bounds__(256) void invdeg_kernel(const float* __restrict__ deg,
                                                     float* __restrict__ invdeg, int n) {
    int i = blockIdx.x * 256 + threadIdx.x;
    if (i < n) invdeg[i] = 1.0f / fmaxf(deg[i], 1.0f);
}

// One wave (64 lanes) per edge; D=512 floats = 128 float4; each lane handles 2 float4.
__global__ __launch_bounds__(256) void scatter_kernel(const float* __restrict__ X,
                                                      const int* __restrict__ src,
                                                      const int* __restrict__ dst,
                                                      float* __restrict__ agg, int E) {
    int gw = (blockIdx.x * 256 + threadIdx.x) >> 6;
    int lane = threadIdx.x & 63;
    if (gw >= E) return;
    int s = src[gw];
    int d = dst[gw];
    const float4* xr = (const float4*)(X + (size_t)s * 512);
    float* ar = agg + (size_t)d * 512;
#pragma unroll
    for (int i = 0; i < 2; ++i) {
        int idx = i * 64 + lane;           // float4 index, coalesced across lanes
        float4 v = xr[idx];
        int b = idx * 4;
        atomicAdd(ar + b + 0, v.x);
        atomicAdd(ar + b + 1, v.y);
        atomicAdd(ar + b + 2, v.z);
        atomicAdd(ar + b + 3, v.w);
    }
}

// C[M,N] = (A1 * scale1[row]) @ B1 + A2 @ B2 + bias, optional relu.
// BM=BN=64, BK=16, 256 threads, 4x4 micro-tile per thread.
__global__ __launch_bounds__(256) void gemm_sage(const float* __restrict__ A1,
                                                 const float* __restrict__ scale1,
                                                 const float* __restrict__ A2,
                                                 const float* __restrict__ B1,
                                                 const float* __restrict__ B2,
                                                 const float* __restrict__ bias,
                                                 float* __restrict__ C,
                                                 int M, int K, int N, int relu) {
    __shared__ float As[16][68];   // [k][m], padded row stride 68 (272B, 16B-aligned)
    __shared__ float Bs[16][64];   // [k][n]

    const int col0 = blockIdx.x * 64;
    const int row0 = blockIdx.y * 64;
    const int t = threadIdx.x;
    const int tm = t >> 4;          // 0..15
    const int tn = t & 15;          // 0..15
    const int la_m = t >> 2;        // 0..63
    const int la_k = (t & 3) * 4;   // 0,4,8,12
    const int lb_k = t >> 4;        // 0..15
    const int lb_n = (t & 15) * 4;  // 0..60

    float acc[4][4];
#pragma unroll
    for (int i = 0; i < 4; ++i)
#pragma unroll
        for (int j = 0; j < 4; ++j) acc[i][j] = 0.f;

    const int arow = row0 + la_m;
    const bool arow_ok = arow < M;
    const float s1 = arow_ok ? scale1[arow] : 0.f;

    for (int pass = 0; pass < 2; ++pass) {
        const float* __restrict__ A = pass ? A2 : A1;
        const float* __restrict__ B = pass ? B2 : B1;
        for (int k0 = 0; k0 < K; k0 += 16) {
            float4 av = make_float4(0.f, 0.f, 0.f, 0.f);
            if (arow_ok) {
                av = *(const float4*)(A + (size_t)arow * K + k0 + la_k);
                if (pass == 0) { av.x *= s1; av.y *= s1; av.z *= s1; av.w *= s1; }
            }
            As[la_k + 0][la_m] = av.x;
            As[la_k + 1][la_m] = av.y;
            As[la_k + 2][la_m] = av.z;
            As[la_k + 3][la_m] = av.w;

            float4 bv = *(const float4*)(B + (size_t)(k0 + lb_k) * N + col0 + lb_n);
            *(float4*)&Bs[lb_k][lb_n] = bv;

            __syncthreads();
#pragma unroll
            for (int kk = 0; kk < 16; ++kk) {
                float4 a = *(const float4*)&As[kk][tm * 4];
                float4 b = *(const float4*)&Bs[kk][tn * 4];
                acc[0][0] += a.x * b.x; acc[0][1] += a.x * b.y; acc[0][2] += a.x * b.z; acc[0][3] += a.x * b.w;
                acc[1][0] += a.y * b.x; acc[1][1] += a.y * b.y; acc[1][2] += a.y * b.z; acc[1][3] += a.y * b.w;
                acc[2][0] += a.z * b.x; acc[2][1] += a.z * b.y; acc[2][2] += a.z * b.z; acc[2][3] += a.z * b.w;
                acc[3][0] += a.w * b.x; acc[3][1] += a.w * b.y; acc[3][2] += a.w * b.z; acc[3][3] += a.w * b.w;
            }
            __syncthreads();
        }
    }

    const int c0 = col0 + tn * 4;
    float4 bb = *(const float4*)(bias + c0);
#pragma unroll
    for (int i = 0; i < 4; ++i) {
        int r = row0 + tm * 4 + i;
        if (r >= M) continue;
        float4 v;
        v.x = acc[i][0] + bb.x;
        v.y = acc[i][1] + bb.y;
        v.z = acc[i][2] + bb.z;
        v.w = acc[i][3] + bb.w;
        if (relu) {
            v.x = fmaxf(v.x, 0.f); v.y = fmaxf(v.y, 0.f);
            v.z = fmaxf(v.z, 0.f); v.w = fmaxf(v.w, 0.f);
        }
        *(float4*)(C + (size_t)r * N + c0) = v;
    }
}

// In-place log_softmax over rows of 128; one wave per row, 4 rows per block.
__global__ __launch_bounds__(256) void logsoftmax128(float* __restrict__ out, int M) {
    int row = blockIdx.x * 4 + (threadIdx.x >> 6);
    int lane = threadIdx.x & 63;
    if (row >= M) return;
    float* p = out + (size_t)row * 128;
    float a = p[lane];
    float b = p[lane + 64];
    float m = fmaxf(a, b);
#pragma unroll
    for (int off = 32; off > 0; off >>= 1) m = fmaxf(m, __shfl_xor(m, off));
    float s = expf(a - m) + expf(b - m);
#pragma unroll
    for (int off = 32; off > 0; off >>= 1) s += __shfl_xor(s, off);
    float ls = m + logf(s);
    p[lane] = a - ls;
    p[lane + 64] = b - ls;
}

extern "C" void kernel_launch(void* const* d_in, const int* in_sizes, int n_in,
                              void* d_out, int out_size, void* d_ws, size_t ws_size,
                              hipStream_t stream) {
    const float* x    = (const float*)d_in[0];
    const int*   ei   = (const int*)d_in[1];
    const float* W1_l = (const float*)d_in[2];
    const float* b1   = (const float*)d_in[3];
    const float* W1_r = (const float*)d_in[4];
    const float* W2_l = (const float*)d_in[5];
    const float* b2   = (const float*)d_in[6];
    const float* W2_r = (const float*)d_in[7];
    const float* W3_l = (const float*)d_in[8];
    const float* b3   = (const float*)d_in[9];
    const float* W3_r = (const float*)d_in[10];
    float* out = (float*)d_out;

    const int* src = ei;
    const int* dst = ei + N_EDGES;

    // Workspace layout (floats):
    float* ws     = (float*)d_ws;
    float* deg    = ws;                    // 50048
    float* invdeg = ws + 50048;            // 50048
    float* agg    = ws + 100096;           // 25,600,000
    float* h1     = agg + 25600000;        // 25,600,000
    float* h2     = h1 + 25600000;         // 25,600,000
    // total: 76,900,096 floats = 307.6 MB

    const int E = N_EDGES, M = N_NODES;
    const int scatter_blocks = (E * 64 + 255) / 256;  // 1 wave per edge

    // zero [deg .. agg end): 100096 + 25,600,000 floats = 6,425,024 float4
    {
        int n4 = (100096 + 25600000) / 4;
        zero4_kernel<<<(n4 + 255) / 256, 256, 0, stream>>>((float4*)ws, n4);
    }
    deg_kernel<<<(E + 255) / 256, 256, 0, stream>>>(dst, deg, E);
    invdeg_kernel<<<(M + 255) / 256, 256, 0, stream>>>(deg, invdeg, M);

    // ---- layer 1: x -> h1 (relu) ----
    scatter_kernel<<<scatter_blocks, 256, 0, stream>>>(x, src, dst, agg, E);
    gemm_sage<<<dim3(512 / 64, (M + 63) / 64), 256, 0, stream>>>(
        agg, invdeg, x, W1_l, W1_r, b1, h1, M, 512, 512, 1);

    // ---- layer 2: h1 -> h2 (relu) ----
    {
        int n4 = 25600000 / 4;
        zero4_kernel<<<(n4 + 255) / 256, 256, 0, stream>>>((float4*)agg, n4);
    }
    scatter_kernel<<<scatter_blocks, 256, 0, stream>>>(h1, src, dst, agg, E);
    gemm_sage<<<dim3(512 / 64, (M + 63) / 64), 256, 0, stream>>>(
        agg, invdeg, h1, W2_l, W2_r, b2, h2, M, 512, 512, 1);

    // ---- layer 3: h2 -> out (no relu), then log_softmax ----
    {
        int n4 = 25600000 / 4;
        zero4_kernel<<<(n4 + 255) / 256, 256, 0, stream>>>((float4*)agg, n4);
    }
    scatter_kernel<<<scatter_blocks, 256, 0, stream>>>(h2, src, dst, agg, E);
    gemm_sage<<<dim3(128 / 64, (M + 63) / 64), 256, 0, stream>>>(
        agg, invdeg, h2, W3_l, W3_r, b3, out, M, 512, 128, 0);

    logsoftmax128<<<(M + 3) / 4, 256, 0, stream>>>(out, M);
}

// Round 2
// 2222.872 us; speedup vs baseline: 4.3631x; 4.3631x over previous
//
#include <hip/hip_runtime.h>
#include <hip/hip_bf16.h>

// GraphSAGE 3-layer, N=50000 nodes, E=400000 edges, dims 512->512->512->128.
// Round 1 -> 2 change: atomic scatter (2653us x3, RMW wall) replaced by
// CSR build + wave-per-node register gather (no feature atomics).
//  - CSR built per call: histogram -> 3-kernel exclusive scan -> placement
//  - gather: 1 wave/node, float4 register accumulation, 1/deg folded in
//  - fused GEMM: C = mean_agg@W_l + X@W_r + b, optional relu (fp32)
//  - in-place log_softmax on d_out

#define N_NODES 50000
#define N_EDGES 400000

__global__ __launch_bounds__(256) void zero4_kernel(float4* __restrict__ p, int n4) {
    int i = blockIdx.x * 256 + threadIdx.x;
    if (i < n4) p[i] = make_float4(0.f, 0.f, 0.f, 0.f);
}

__global__ __launch_bounds__(256) void hist_kernel(const int* __restrict__ dst,
                                                   int* __restrict__ deg, int E) {
    int e = blockIdx.x * 256 + threadIdx.x;
    if (e < E) atomicAdd(&deg[dst[e]], 1);
}

// --- 3-kernel exclusive scan over n=50000 ints (in place in row_start) ---
__global__ __launch_bounds__(256) void scan_reduce(const int* __restrict__ v,
                                                   int* __restrict__ bsums, int n) {
    __shared__ int sh[256];
    int i = blockIdx.x * 256 + threadIdx.x;
    sh[threadIdx.x] = (i < n) ? v[i] : 0;
    __syncthreads();
    for (int off = 128; off > 0; off >>= 1) {
        if (threadIdx.x < off) sh[threadIdx.x] += sh[threadIdx.x + off];
        __syncthreads();
    }
    if (threadIdx.x == 0) bsums[blockIdx.x] = sh[0];
}

__global__ __launch_bounds__(256) void scan_sums(int* __restrict__ bsums, int nb) {
    // single block; exclusive scan of bsums[0..nb), nb <= 256
    __shared__ int sh[256];
    int t = threadIdx.x;
    int val = (t < nb) ? bsums[t] : 0;
    sh[t] = val;
    __syncthreads();
    for (int off = 1; off < 256; off <<= 1) {
        int v = (t >= off) ? sh[t - off] : 0;
        __syncthreads();
        sh[t] += v;
        __syncthreads();
    }
    if (t < nb) bsums[t] = sh[t] - val;   // exclusive
}

__global__ __launch_bounds__(256) void scan_final(int* __restrict__ v,
                                                  const int* __restrict__ bsums, int n) {
    __shared__ int sh[256];
    int t = threadIdx.x;
    int i = blockIdx.x * 256 + t;
    int val = (i < n) ? v[i] : 0;
    sh[t] = val;
    __syncthreads();
    for (int off = 1; off < 256; off <<= 1) {
        int x = (t >= off) ? sh[t - off] : 0;
        __syncthreads();
        sh[t] += x;
        __syncthreads();
    }
    int excl = sh[t] - val + bsums[blockIdx.x];
    if (i < n) v[i] = excl;
    if (i == n - 1) v[n] = excl + val;   // row_start[n] = total = E
}

__global__ __launch_bounds__(256) void fill_kernel(const int* __restrict__ src,
                                                   const int* __restrict__ dst,
                                                   const int* __restrict__ row_start,
                                                   int* __restrict__ cursor,
                                                   int* __restrict__ csr_src, int E) {
    int e = blockIdx.x * 256 + threadIdx.x;
    if (e < E) {
        int d = dst[e];
        int pos = row_start[d] + atomicAdd(&cursor[d], 1);
        csr_src[pos] = src[e];
    }
}

// One wave per node: accumulate mean of neighbor rows into registers.
// D=512 floats = 128 float4; lane handles float4 [lane] and [lane+64].
__global__ __launch_bounds__(256) void gather_mean(const float* __restrict__ X,
                                                   const int* __restrict__ row_start,
                                                   const int* __restrict__ csr_src,
                                                   float* __restrict__ agg, int M) {
    int node = (blockIdx.x * 256 + threadIdx.x) >> 6;
    int lane = threadIdx.x & 63;
    if (node >= M) return;
    int beg = row_start[node], end = row_start[node + 1];
    float4 a0 = make_float4(0.f, 0.f, 0.f, 0.f);
    float4 a1 = make_float4(0.f, 0.f, 0.f, 0.f);
    for (int c = beg; c < end; c += 64) {
        int nb = min(64, end - c);
        int eid = (lane < nb) ? csr_src[c + lane] : 0;
        for (int i = 0; i < nb; ++i) {
            int s = __shfl(eid, i);
            const float4* xr = (const float4*)(X + (size_t)s * 512);
            float4 v0 = xr[lane];
            float4 v1 = xr[lane + 64];
            a0.x += v0.x; a0.y += v0.y; a0.z += v0.z; a0.w += v0.w;
            a1.x += v1.x; a1.y += v1.y; a1.z += v1.z; a1.w += v1.w;
        }
    }
    float inv = 1.0f / fmaxf((float)(end - beg), 1.0f);
    a0.x *= inv; a0.y *= inv; a0.z *= inv; a0.w *= inv;
    a1.x *= inv; a1.y *= inv; a1.z *= inv; a1.w *= inv;
    float4* ar = (float4*)(agg + (size_t)node * 512);
    ar[lane] = a0;
    ar[lane + 64] = a1;
}

// C[M,N] = A1 @ B1 + A2 @ B2 + bias, optional relu.
// BM=BN=64, BK=16, 256 threads, 4x4 micro-tile per thread.
__global__ __launch_bounds__(256) void gemm_sage(const float* __restrict__ A1,
                                                 const float* __restrict__ A2,
                                                 const float* __restrict__ B1,
                                                 const float* __restrict__ B2,
                                                 const float* __restrict__ bias,
                                                 float* __restrict__ C,
                                                 int M, int K, int N, int relu) {
    __shared__ float As[16][68];   // [k][m], padded
    __shared__ float Bs[16][64];   // [k][n]

    const int col0 = blockIdx.x * 64;
    const int row0 = blockIdx.y * 64;
    const int t = threadIdx.x;
    const int tm = t >> 4;
    const int tn = t & 15;
    const int la_m = t >> 2;
    const int la_k = (t & 3) * 4;
    const int lb_k = t >> 4;
    const int lb_n = (t & 15) * 4;

    float acc[4][4];
#pragma unroll
    for (int i = 0; i < 4; ++i)
#pragma unroll
        for (int j = 0; j < 4; ++j) acc[i][j] = 0.f;

    const int arow = row0 + la_m;
    const bool arow_ok = arow < M;

    for (int pass = 0; pass < 2; ++pass) {
        const float* __restrict__ A = pass ? A2 : A1;
        const float* __restrict__ B = pass ? B2 : B1;
        for (int k0 = 0; k0 < K; k0 += 16) {
            float4 av = make_float4(0.f, 0.f, 0.f, 0.f);
            if (arow_ok) av = *(const float4*)(A + (size_t)arow * K + k0 + la_k);
            As[la_k + 0][la_m] = av.x;
            As[la_k + 1][la_m] = av.y;
            As[la_k + 2][la_m] = av.z;
            As[la_k + 3][la_m] = av.w;

            float4 bv = *(const float4*)(B + (size_t)(k0 + lb_k) * N + col0 + lb_n);
            *(float4*)&Bs[lb_k][lb_n] = bv;

            __syncthreads();
#pragma unroll
            for (int kk = 0; kk < 16; ++kk) {
                float4 a = *(const float4*)&As[kk][tm * 4];
                float4 b = *(const float4*)&Bs[kk][tn * 4];
                acc[0][0] += a.x * b.x; acc[0][1] += a.x * b.y; acc[0][2] += a.x * b.z; acc[0][3] += a.x * b.w;
                acc[1][0] += a.y * b.x; acc[1][1] += a.y * b.y; acc[1][2] += a.y * b.z; acc[1][3] += a.y * b.w;
                acc[2][0] += a.z * b.x; acc[2][1] += a.z * b.y; acc[2][2] += a.z * b.z; acc[2][3] += a.z * b.w;
                acc[3][0] += a.w * b.x; acc[3][1] += a.w * b.y; acc[3][2] += a.w * b.z; acc[3][3] += a.w * b.w;
            }
            __syncthreads();
        }
    }

    const int c0 = col0 + tn * 4;
    float4 bb = *(const float4*)(bias + c0);
#pragma unroll
    for (int i = 0; i < 4; ++i) {
        int r = row0 + tm * 4 + i;
        if (r >= M) continue;
        float4 v;
        v.x = acc[i][0] + bb.x;
        v.y = acc[i][1] + bb.y;
        v.z = acc[i][2] + bb.z;
        v.w = acc[i][3] + bb.w;
        if (relu) {
            v.x = fmaxf(v.x, 0.f); v.y = fmaxf(v.y, 0.f);
            v.z = fmaxf(v.z, 0.f); v.w = fmaxf(v.w, 0.f);
        }
        *(float4*)(C + (size_t)r * N + c0) = v;
    }
}

// In-place log_softmax over rows of 128; one wave per row, 4 rows per block.
__global__ __launch_bounds__(256) void logsoftmax128(float* __restrict__ out, int M) {
    int row = blockIdx.x * 4 + (threadIdx.x >> 6);
    int lane = threadIdx.x & 63;
    if (row >= M) return;
    float* p = out + (size_t)row * 128;
    float a = p[lane];
    float b = p[lane + 64];
    float m = fmaxf(a, b);
#pragma unroll
    for (int off = 32; off > 0; off >>= 1) m = fmaxf(m, __shfl_xor(m, off));
    float s = expf(a - m) + expf(b - m);
#pragma unroll
    for (int off = 32; off > 0; off >>= 1) s += __shfl_xor(s, off);
    float ls = m + logf(s);
    p[lane] = a - ls;
    p[lane + 64] = b - ls;
}

extern "C" void kernel_launch(void* const* d_in, const int* in_sizes, int n_in,
                              void* d_out, int out_size, void* d_ws, size_t ws_size,
                              hipStream_t stream) {
    const float* x    = (const float*)d_in[0];
    const int*   ei   = (const int*)d_in[1];
    const float* W1_l = (const float*)d_in[2];
    const float* b1   = (const float*)d_in[3];
    const float* W1_r = (const float*)d_in[4];
    const float* W2_l = (const float*)d_in[5];
    const float* b2   = (const float*)d_in[6];
    const float* W2_r = (const float*)d_in[7];
    const float* W3_l = (const float*)d_in[8];
    const float* b3   = (const float*)d_in[9];
    const float* W3_r = (const float*)d_in[10];
    float* out = (float*)d_out;

    const int* src = ei;
    const int* dst = ei + N_EDGES;

    // Workspace layout:
    int* row_start = (int*)d_ws;                    // 50052 (uses 50001)
    int* cursor    = row_start + 50052;             // 50052 (uses 50000)
    int* bsums     = cursor + 50052;                // 512   (uses 196)
    int* csr_src   = bsums + 512;                   // 400000
    float* agg = (float*)(csr_src + 400000);        // 25,600,000  (offset 16B-aligned)
    float* h1  = agg + 25600000;                    // 25,600,000
    float* h2  = h1 + 25600000;                     // 25,600,000

    const int E = N_EDGES, M = N_NODES;
    const int nblk = (M + 255) / 256;               // 196 scan blocks

    // ---- CSR build ----
    // zero row_start+cursor+bsums: 50052+50052+512 = 100616 ints = 25154 float4
    zero4_kernel<<<(25154 + 255) / 256, 256, 0, stream>>>((float4*)d_ws, 25154);
    hist_kernel<<<(E + 255) / 256, 256, 0, stream>>>(dst, row_start, E);
    scan_reduce<<<nblk, 256, 0, stream>>>(row_start, bsums, M);
    scan_sums<<<1, 256, 0, stream>>>(bsums, nblk);
    scan_final<<<nblk, 256, 0, stream>>>(row_start, bsums, M);
    fill_kernel<<<(E + 255) / 256, 256, 0, stream>>>(src, dst, row_start, cursor,
                                                     csr_src, E);

    const int gather_blocks = (M * 64 + 255) / 256;  // 1 wave per node

    // ---- layer 1: x -> h1 (relu) ----
    gather_mean<<<gather_blocks, 256, 0, stream>>>(x, row_start, csr_src, agg, M);
    gemm_sage<<<dim3(512 / 64, (M + 63) / 64), 256, 0, stream>>>(
        agg, x, W1_l, W1_r, b1, h1, M, 512, 512, 1);

    // ---- layer 2: h1 -> h2 (relu) ----
    gather_mean<<<gather_blocks, 256, 0, stream>>>(h1, row_start, csr_src, agg, M);
    gemm_sage<<<dim3(512 / 64, (M + 63) / 64), 256, 0, stream>>>(
        agg, h1, W2_l, W2_r, b2, h2, M, 512, 512, 1);

    // ---- layer 3: h2 -> out (no relu), then log_softmax ----
    gather_mean<<<gather_blocks, 256, 0, stream>>>(h2, row_start, csr_src, agg, M);
    gemm_sage<<<dim3(128 / 64, (M + 63) / 64), 256, 0, stream>>>(
        agg, h2, W3_l, W3_r, b3, out, M, 512, 128, 0);

    logsoftmax128<<<(M + 3) / 4, 256, 0, stream>>>(out, M);
}

// Round 3
// 860.794 us; speedup vs baseline: 11.2671x; 2.5824x over previous
//
#include <hip/hip_runtime.h>
#include <hip/hip_bf16.h>

// GraphSAGE 3-layer, N=50000 nodes, E=400000 edges, dims 512->512->512->128.
// Round 2 -> 3: fp32 VALU GEMM (68 TF, MfmaUtil=0) -> bf16 MFMA GEMM
// (mfma_f32_16x16x32_bf16, m97-style 128x128 tile, global_load_lds w=16).
//  - features bf16 end-to-end (x converted once; gather and GEMM epilogue
//    emit bf16), fp32 accumulate everywhere
//  - weights transposed to W^T[N][K] bf16 once per call (k-contiguous)
//  - CSR build + wave-per-node gather unchanged from round 2

#define N_NODES 50000
#define N_EDGES 400000

typedef unsigned short u16;
typedef unsigned int u32;
typedef __attribute__((ext_vector_type(8))) short short8;
typedef __attribute__((ext_vector_type(4))) float floatx4;

__device__ __forceinline__ u16 f32_to_bf16(float f) {
    u32 u = __float_as_uint(f);
    u32 r = 0x7FFFu + ((u >> 16) & 1u);
    return (u16)((u + r) >> 16);
}
__device__ __forceinline__ float bf16_to_f32(u32 lo16) {
    return __uint_as_float(lo16 << 16);
}
__device__ __forceinline__ void async16(const u16* g, u16* l) {
    __builtin_amdgcn_global_load_lds(
        (const __attribute__((address_space(1))) u32*)g,
        (__attribute__((address_space(3))) u32*)l, 16, 0, 0);
}

__global__ __launch_bounds__(256) void zero4_kernel(float4* __restrict__ p, int n4) {
    int i = blockIdx.x * 256 + threadIdx.x;
    if (i < n4) p[i] = make_float4(0.f, 0.f, 0.f, 0.f);
}

__global__ __launch_bounds__(256) void hist_kernel(const int* __restrict__ dst,
                                                   int* __restrict__ deg, int E) {
    int e = blockIdx.x * 256 + threadIdx.x;
    if (e < E) atomicAdd(&deg[dst[e]], 1);
}

__global__ __launch_bounds__(256) void scan_reduce(const int* __restrict__ v,
                                                   int* __restrict__ bsums, int n) {
    __shared__ int sh[256];
    int i = blockIdx.x * 256 + threadIdx.x;
    sh[threadIdx.x] = (i < n) ? v[i] : 0;
    __syncthreads();
    for (int off = 128; off > 0; off >>= 1) {
        if (threadIdx.x < off) sh[threadIdx.x] += sh[threadIdx.x + off];
        __syncthreads();
    }
    if (threadIdx.x == 0) bsums[blockIdx.x] = sh[0];
}

__global__ __launch_bounds__(256) void scan_sums(int* __restrict__ bsums, int nb) {
    __shared__ int sh[256];
    int t = threadIdx.x;
    int val = (t < nb) ? bsums[t] : 0;
    sh[t] = val;
    __syncthreads();
    for (int off = 1; off < 256; off <<= 1) {
        int v = (t >= off) ? sh[t - off] : 0;
        __syncthreads();
        sh[t] += v;
        __syncthreads();
    }
    if (t < nb) bsums[t] = sh[t] - val;
}

__global__ __launch_bounds__(256) void scan_final(int* __restrict__ v,
                                                  const int* __restrict__ bsums, int n) {
    __shared__ int sh[256];
    int t = threadIdx.x;
    int i = blockIdx.x * 256 + t;
    int val = (i < n) ? v[i] : 0;
    sh[t] = val;
    __syncthreads();
    for (int off = 1; off < 256; off <<= 1) {
        int x = (t >= off) ? sh[t - off] : 0;
        __syncthreads();
        sh[t] += x;
        __syncthreads();
    }
    int excl = sh[t] - val + bsums[blockIdx.x];
    if (i < n) v[i] = excl;
    if (i == n - 1) v[n] = excl + val;
}

__global__ __launch_bounds__(256) void fill_kernel(const int* __restrict__ src,
                                                   const int* __restrict__ dst,
                                                   const int* __restrict__ row_start,
                                                   int* __restrict__ cursor,
                                                   int* __restrict__ csr_src, int E) {
    int e = blockIdx.x * 256 + threadIdx.x;
    if (e < E) {
        int d = dst[e];
        int pos = row_start[d] + atomicAdd(&cursor[d], 1);
        csr_src[pos] = src[e];
    }
}

// f32 [n8*8] -> bf16, 8 elems/thread
__global__ __launch_bounds__(256) void convert_bf16(const float* __restrict__ in,
                                                    u16* __restrict__ out, int n8) {
    int i = blockIdx.x * 256 + threadIdx.x;
    if (i >= n8) return;
    const float4* p = (const float4*)in + (size_t)i * 2;
    float4 v0 = p[0], v1 = p[1];
    uint4 o;
    o.x = (u32)f32_to_bf16(v0.x) | ((u32)f32_to_bf16(v0.y) << 16);
    o.y = (u32)f32_to_bf16(v0.z) | ((u32)f32_to_bf16(v0.w) << 16);
    o.z = (u32)f32_to_bf16(v1.x) | ((u32)f32_to_bf16(v1.y) << 16);
    o.w = (u32)f32_to_bf16(v1.z) | ((u32)f32_to_bf16(v1.w) << 16);
    ((uint4*)out)[i] = o;
}

// W [K][N] f32 -> WT [N][K] bf16, 32x32 tiles
__global__ __launch_bounds__(256) void transpose_w(const float* __restrict__ W,
                                                   u16* __restrict__ WT,
                                                   int K, int N) {
    __shared__ float t[32][33];
    int n0 = blockIdx.x * 32, k0 = blockIdx.y * 32;
    int c = threadIdx.x & 31, r0 = threadIdx.x >> 5;  // r0 in 0..7
    for (int r = r0; r < 32; r += 8)
        t[r][c] = W[(size_t)(k0 + r) * N + n0 + c];
    __syncthreads();
    for (int r = r0; r < 32; r += 8)
        WT[(size_t)(n0 + r) * K + k0 + c] = f32_to_bf16(t[c][r]);
}

// One wave per node: mean of neighbor bf16 rows, fp32 accum, bf16 out.
// D=512 bf16 = 1KB/row = 64 lanes x 16B exactly.
__global__ __launch_bounds__(256) void gather_mean_bf16(const u16* __restrict__ X,
                                                        const int* __restrict__ row_start,
                                                        const int* __restrict__ csr_src,
                                                        u16* __restrict__ agg, int M) {
    int node = (blockIdx.x * 256 + threadIdx.x) >> 6;
    int lane = threadIdx.x & 63;
    if (node >= M) return;
    int beg = row_start[node], end = row_start[node + 1];
    float a[8] = {0.f, 0.f, 0.f, 0.f, 0.f, 0.f, 0.f, 0.f};
    for (int c = beg; c < end; c += 64) {
        int nb = min(64, end - c);
        int eid = (lane < nb) ? csr_src[c + lane] : 0;
        for (int i = 0; i < nb; ++i) {
            int s = __shfl(eid, i);
            uint4 v = ((const uint4*)(X + (size_t)s * 512))[lane];
            a[0] += bf16_to_f32(v.x & 0xffffu); a[1] += bf16_to_f32(v.x >> 16);
            a[2] += bf16_to_f32(v.y & 0xffffu); a[3] += bf16_to_f32(v.y >> 16);
            a[4] += bf16_to_f32(v.z & 0xffffu); a[5] += bf16_to_f32(v.z >> 16);
            a[6] += bf16_to_f32(v.w & 0xffffu); a[7] += bf16_to_f32(v.w >> 16);
        }
    }
    float inv = 1.0f / fmaxf((float)(end - beg), 1.0f);
    uint4 o;
    o.x = (u32)f32_to_bf16(a[0] * inv) | ((u32)f32_to_bf16(a[1] * inv) << 16);
    o.y = (u32)f32_to_bf16(a[2] * inv) | ((u32)f32_to_bf16(a[3] * inv) << 16);
    o.z = (u32)f32_to_bf16(a[4] * inv) | ((u32)f32_to_bf16(a[5] * inv) << 16);
    o.w = (u32)f32_to_bf16(a[6] * inv) | ((u32)f32_to_bf16(a[7] * inv) << 16);
    ((uint4*)(agg + (size_t)node * 512))[lane] = o;
}

// C[M,N] = A1@B1T' + A2@B2T' + bias (B*T stored [N][K]), optional relu.
// 128x128 tile, BK=32, 4 waves, each wave 4x4 of 16x16x32 MFMA.
// LDS layout: granule g = kq*128 + r (r = row-in-tile), 16B per granule,
// exactly matching global_load_lds's wave-uniform-base + lane*16 rule.
__global__ __launch_bounds__(256) void gemm_bf16(
    const u16* __restrict__ A1, const u16* __restrict__ A2,
    const u16* __restrict__ B1T, const u16* __restrict__ B2T,
    const float* __restrict__ bias,
    u16* __restrict__ Cb, float* __restrict__ Cf,
    int M, int K, int N, int relu) {
    __shared__ u16 As[4096];  // 4 kq-chunks * 128 granules * 8 bf16 = 8KB
    __shared__ u16 Bs[4096];

    const int t = threadIdx.x;
    const int w = t >> 6, lane = t & 63;
    const int wm = (w >> 1) * 64, wn = (w & 1) * 64;
    const int row0 = blockIdx.y * 128, col0 = blockIdx.x * 128;
    const int l15 = lane & 15, kq = lane >> 4;

    floatx4 acc[4][4];
#pragma unroll
    for (int i = 0; i < 4; ++i)
#pragma unroll
        for (int j = 0; j < 4; ++j) acc[i][j] = floatx4{0.f, 0.f, 0.f, 0.f};

    // Staging: wave w owns kq-chunk w; instr i covers rows i*64+lane.
    size_t aoff[2], boff[2];
#pragma unroll
    for (int i = 0; i < 2; ++i) {
        int ar = min(row0 + i * 64 + lane, M - 1);
        aoff[i] = (size_t)ar * K + (size_t)(w * 8);
        int bn = col0 + i * 64 + lane;  // N % 128 == 0, always valid
        boff[i] = (size_t)bn * K + (size_t)(w * 8);
    }
    u16* ldsA0 = &As[(w * 128 + 0) * 8];
    u16* ldsA1 = &As[(w * 128 + 64) * 8];
    u16* ldsB0 = &Bs[(w * 128 + 0) * 8];
    u16* ldsB1 = &Bs[(w * 128 + 64) * 8];

    const short8* Asv = (const short8*)As;
    const short8* Bsv = (const short8*)Bs;

    for (int pass = 0; pass < 2; ++pass) {
        const u16* Ap = pass ? A2 : A1;
        const u16* Bp = pass ? B2T : B1T;
        for (int k0 = 0; k0 < K; k0 += 32) {
            async16(Ap + aoff[0] + k0, ldsA0);
            async16(Ap + aoff[1] + k0, ldsA1);
            async16(Bp + boff[0] + k0, ldsB0);
            async16(Bp + boff[1] + k0, ldsB1);
            __syncthreads();

            short8 a[4], b[4];
#pragma unroll
            for (int mt = 0; mt < 4; ++mt)
                a[mt] = Asv[kq * 128 + wm + mt * 16 + l15];
#pragma unroll
            for (int nt = 0; nt < 4; ++nt)
                b[nt] = Bsv[kq * 128 + wn + nt * 16 + l15];
#pragma unroll
            for (int mt = 0; mt < 4; ++mt)
#pragma unroll
                for (int nt = 0; nt < 4; ++nt)
                    acc[mt][nt] = __builtin_amdgcn_mfma_f32_16x16x32_bf16(
                        a[mt], b[nt], acc[mt][nt], 0, 0, 0);
            __syncthreads();
        }
    }

    // Epilogue. C/D: col = lane&15, row = (lane>>4)*4 + reg  [m89/m91]
#pragma unroll
    for (int nt = 0; nt < 4; ++nt) {
        int col = col0 + wn + nt * 16 + l15;
        float bv = bias[col];
#pragma unroll
        for (int mt = 0; mt < 4; ++mt) {
#pragma unroll
            for (int r = 0; r < 4; ++r) {
                int row = row0 + wm + mt * 16 + kq * 4 + r;
                if (row >= M) continue;
                float v = acc[mt][nt][r] + bv;
                if (relu) v = fmaxf(v, 0.f);
                if (Cf) Cf[(size_t)row * N + col] = v;
                else Cb[(size_t)row * N + col] = f32_to_bf16(v);
            }
        }
    }
}

// In-place log_softmax over rows of 128; one wave per row.
__global__ __launch_bounds__(256) void logsoftmax128(float* __restrict__ out, int M) {
    int row = blockIdx.x * 4 + (threadIdx.x >> 6);
    int lane = threadIdx.x & 63;
    if (row >= M) return;
    float* p = out + (size_t)row * 128;
    float a = p[lane];
    float b = p[lane + 64];
    float m = fmaxf(a, b);
#pragma unroll
    for (int off = 32; off > 0; off >>= 1) m = fmaxf(m, __shfl_xor(m, off));
    float s = expf(a - m) + expf(b - m);
#pragma unroll
    for (int off = 32; off > 0; off >>= 1) s += __shfl_xor(s, off);
    float ls = m + logf(s);
    p[lane] = a - ls;
    p[lane + 64] = b - ls;
}

extern "C" void kernel_launch(void* const* d_in, const int* in_sizes, int n_in,
                              void* d_out, int out_size, void* d_ws, size_t ws_size,
                              hipStream_t stream) {
    const float* x    = (const float*)d_in[0];
    const int*   ei   = (const int*)d_in[1];
    const float* W1_l = (const float*)d_in[2];
    const float* b1   = (const float*)d_in[3];
    const float* W1_r = (const float*)d_in[4];
    const float* W2_l = (const float*)d_in[5];
    const float* b2   = (const float*)d_in[6];
    const float* W2_r = (const float*)d_in[7];
    const float* W3_l = (const float*)d_in[8];
    const float* b3   = (const float*)d_in[9];
    const float* W3_r = (const float*)d_in[10];
    float* out = (float*)d_out;

    const int* src = ei;
    const int* dst = ei + N_EDGES;

    // Workspace layout (bytes from base):
    char* base = (char*)d_ws;
    int* row_start = (int*)(base);                    // 50052 ints
    int* cursor    = (int*)(base + 200208);           // 50052 ints
    int* bsums     = (int*)(base + 400416);           // 512 ints
    int* csr_src   = (int*)(base + 402464);           // 400000 ints -> end 2002464
    u16* xb   = (u16*)(base + 2002464);               // 25.6M bf16
    u16* aggb = (u16*)(base + 53202464);
    u16* h1b  = (u16*)(base + 104402464);
    u16* h2b  = (u16*)(base + 155602464);
    u16* w1lT = (u16*)(base + 206802464);             // [512][512]
    u16* w1rT = (u16*)(base + 207326752);
    u16* w2lT = (u16*)(base + 207851040);
    u16* w2rT = (u16*)(base + 208375328);
    u16* w3lT = (u16*)(base + 208899616);             // [128][512]
    u16* w3rT = (u16*)(base + 209030688);             // end 209161760

    const int E = N_EDGES, M = N_NODES;
    const int nblk = (M + 255) / 256;

    // ---- CSR build ----
    zero4_kernel<<<(25154 + 255) / 256, 256, 0, stream>>>((float4*)d_ws, 25154);
    hist_kernel<<<(E + 255) / 256, 256, 0, stream>>>(dst, row_start, E);
    scan_reduce<<<nblk, 256, 0, stream>>>(row_start, bsums, M);
    scan_sums<<<1, 256, 0, stream>>>(bsums, nblk);
    scan_final<<<nblk, 256, 0, stream>>>(row_start, bsums, M);
    fill_kernel<<<(E + 255) / 256, 256, 0, stream>>>(src, dst, row_start, cursor,
                                                     csr_src, E);

    // ---- conversions ----
    convert_bf16<<<(3200000 + 255) / 256, 256, 0, stream>>>(x, xb, 3200000);
    transpose_w<<<dim3(16, 16), 256, 0, stream>>>(W1_l, w1lT, 512, 512);
    transpose_w<<<dim3(16, 16), 256, 0, stream>>>(W1_r, w1rT, 512, 512);
    transpose_w<<<dim3(16, 16), 256, 0, stream>>>(W2_l, w2lT, 512, 512);
    transpose_w<<<dim3(16, 16), 256, 0, stream>>>(W2_r, w2rT, 512, 512);
    transpose_w<<<dim3(4, 16), 256, 0, stream>>>(W3_l, w3lT, 512, 128);
    transpose_w<<<dim3(4, 16), 256, 0, stream>>>(W3_r, w3rT, 512, 128);

    const int gather_blocks = (M * 64 + 255) / 256;
    const int gy = (M + 127) / 128;  // 391

    // ---- layer 1 ----
    gather_mean_bf16<<<gather_blocks, 256, 0, stream>>>(xb, row_start, csr_src, aggb, M);
    gemm_bf16<<<dim3(4, gy), 256, 0, stream>>>(aggb, xb, w1lT, w1rT, b1,
                                               h1b, nullptr, M, 512, 512, 1);
    // ---- layer 2 ----
    gather_mean_bf16<<<gather_blocks, 256, 0, stream>>>(h1b, row_start, csr_src, aggb, M);
    gemm_bf16<<<dim3(4, gy), 256, 0, stream>>>(aggb, h1b, w2lT, w2rT, b2,
                                               h2b, nullptr, M, 512, 512, 1);
    // ---- layer 3 ----
    gather_mean_bf16<<<gather_blocks, 256, 0, stream>>>(h2b, row_start, csr_src, aggb, M);
    gemm_bf16<<<dim3(1, gy), 256, 0, stream>>>(aggb, h2b, w3lT, w3rT, b3,
                                               nullptr, out, M, 512, 128, 0);

    logsoftmax128<<<(M + 3) / 4, 256, 0, stream>>>(out, M);
}